// Round 11
// baseline (25.111 us; speedup 1.0000x reference)
//
#include <hip/hip_runtime.h>

// QuantumLayer: boson-sampling distribution + linear head.
//   x:[512,8] f32, thetas:[12] f32, W:[4368,10] f32, b:[10] f32 -> out:[512,10] f32
// Identities:
//   * Columns of U evolve independently under row-ops => evolve only cols 0..4.
//   * Glynn (16 terms, delta_0=+1); sign folded into rs; 2^-4 squared -> 1/256.
//   * Prefix factorization + same-v pairing: two prefixes share each rsp[q][w]
//     load burst; heavy pairs (v<=4) split; 16 named float4 regs (R2 lesson).
//   * R8: permanents -> prob_lds (no globals in hot loop), then dense GEMV.
//   * R10: 60-lane Phase A via __shfl; tables staged to LDS by waves 1-7
//     during Phase A; B+B2 merged; Phase E round-0 prefetch.
//   * R11: compile-time LPT (snake-deal) Phase C schedule. Entries sorted
//     cost-desc and PRE-PERMUTED in the constant table; thread t runs entry t,
//     and threads t>=304 also run entry 1023-t (the 208 smallest). Per-thread
//     load max 96 units vs contiguous-cstart's ~128-160 (cost-boundary
//     quantization). Zero extra traffic; bit-identical per-entry math.
//   Falsified levers (R6/R7/R9): more waves, more blocks, -28% LDS traffic.

#define MODES 12
#define NPH   5
#define KG    16
#define QG    8         // KG/2 packed pairs
#define NPAIR 78        // unordered pairs a<=b
#define S_TOT 4368
#define TPB   512
#define NWAVE (TPB / 64)
#define NOUT  10
#define NENT  720       // 684 pairs + 36 splits (v<=4); 512 + 208 snake layout

#define TWO_PI_F 6.28318530717958647692f
#define RS2      0.70710678118654752440f

// ---------------- compile-time schedule ----------------
constexpr int Cnk(int n, int r) {
  int p = 1;
  for (int i = 0; i < r; ++i) p = p * (n - i) / (i + 1);  // exact stepwise
  return p;
}

struct Tables {
  unsigned       ea[NENT];        // prefix A: code<<29 | sbase<<16 | m0<<12|m1<<8|m2<<4|v
  unsigned       eb[NENT];        // prefix B (== A for self-pairs)
  unsigned char  wr[NENT];        // w0<<4 | w1
  unsigned char  pairs[NPAIR];    // a<<4 | b
};

constexpr Tables make_tables() {
  // ---- 1) generate raw entries (same construction as R9/R10) ----
  unsigned      ra[NENT] = {};
  unsigned      rb[NENT] = {};
  unsigned char rw[NENT] = {};
  int ne = 0;
  for (int v = 11; v >= 0; --v) {
    unsigned P[364] = {};
    int cnt = 0;
    for (int m0 = 0; m0 <= v; ++m0)
      for (int m1 = m0; m1 <= v; ++m1)
        for (int m2 = m1; m2 <= v; ++m2) {
          int sbase = 0;  // lex rank of (m0,m1,m2,v,v) in CWR(12,5)
          for (int q = 0;  q < m0; ++q) sbase += Cnk(15 - q, 4);
          for (int q = m0; q < m1; ++q) sbase += Cnk(14 - q, 3);
          for (int q = m1; q < m2; ++q) sbase += Cnk(13 - q, 2);
          for (int q = m2; q < v;  ++q) sbase += 12 - q;
          // norm code from (pm, run) of the 4-prefix (only 7 combos exist)
          int r1 = 1, pm = 1;
          r1 = (m1 == m0) ? r1 + 1 : 1; pm *= r1;
          r1 = (m2 == m1) ? r1 + 1 : 1; pm *= r1;
          r1 = (v  == m2) ? r1 + 1 : 1; pm *= r1;
          int code = 0;
          if (pm == 1)       code = 0;
          else if (pm == 2)  code = (r1 == 1) ? 1 : 2;
          else if (pm == 4)  code = 3;
          else if (pm == 6)  code = (r1 == 1) ? 4 : 5;
          else               code = 6;   // pm == 24
          P[cnt++] = ((unsigned)code << 29) | ((unsigned)sbase << 16) |
                     ((unsigned)m0 << 12) | ((unsigned)m1 << 8) |
                     ((unsigned)m2 << 4) | (unsigned)v;
        }
    const int np = (cnt + 1) / 2;
    for (int j = 0; j < np; ++j) {
      unsigned a = P[2 * j];
      unsigned b = (2 * j + 1 < cnt) ? P[2 * j + 1] : a;   // self-pair if odd
      if (v <= 4) {                       // split heavy pairs
        int mid = (v + 12) / 2;
        ra[ne] = a; rb[ne] = b; rw[ne] = (unsigned char)((v << 4) | mid);  ne++;
        ra[ne] = a; rb[ne] = b; rw[ne] = (unsigned char)((mid << 4) | 12); ne++;
      } else {
        ra[ne] = a; rb[ne] = b; rw[ne] = (unsigned char)((v << 4) | 12);   ne++;
      }
    }
  }
  // ---- 2) stable counting sort, cost-DESC (cost = 32 + 8*(w1-w0)) ----
  // Emit pre-permuted: slot i = i-th most expensive entry. Snake layout:
  // thread t runs slot t; threads t>=304 also run slot 1023-t.
  Tables T{};
  int idx = 0;
  for (int rng = 7; rng >= 1; --rng)       // w-range 7 (88 units) .. 1 (40)
    for (int i = 0; i < NENT; ++i) {
      int r = (int)(rw[i] & 15u) - (int)(rw[i] >> 4);
      if (r == rng) { T.ea[idx] = ra[i]; T.eb[idx] = rb[i]; T.wr[idx] = rw[i]; ++idx; }
    }
  // unordered pair index table
  int pi = 0;
  for (int a = 0; a < MODES; ++a)
    for (int b = a; b < MODES; ++b)
      T.pairs[pi++] = (unsigned char)((a << 4) | b);
  return T;
}

__constant__ Tables g_tab = make_tables();

// (inv_first, inv_pm) per norm code: inv_pm = 1/(256*pm), inv_first = inv_pm/(run+1)
__constant__ float2 g_normlut[7] = {
  {1.f / 512.f,   1.f / 256.f},    // pm=1,  run=1
  {1.f / 1024.f,  1.f / 512.f},    // pm=2,  run=1
  {1.f / 1536.f,  1.f / 512.f},    // pm=2,  run=2
  {1.f / 3072.f,  1.f / 1024.f},   // pm=4,  run=2
  {1.f / 3072.f,  1.f / 1536.f},   // pm=6,  run=1
  {1.f / 6144.f,  1.f / 1536.f},   // pm=6,  run=3
  {1.f / 30720.f, 1.f / 6144.f},   // pm=24, run=4
};

// ---------------- device kernel ----------------
// prefix products from pair-product table (packed k0,k1)
#define PREFA(q)                                                    \
  { float4 A = ppt[q][p01a], B = ppt[q][p2va];                      \
    pf##q = make_float4(A.x*B.x - A.y*B.y, A.x*B.y + A.y*B.x,       \
                        A.z*B.z - A.w*B.w, A.z*B.w + A.w*B.z); }
#define PREFB(q)                                                    \
  { float4 A = ppt[q][p01b], B = ppt[q][p2vb];                      \
    pg##q = make_float4(A.x*B.x - A.y*B.y, A.x*B.y + A.y*B.x,       \
                        A.z*B.z - A.w*B.w, A.z*B.w + A.w*B.z); }

// one shared rsp load feeds both prefixes' FMAs
#define WSTEP2(q, PRA, PIA, PRB, PIB)                                   \
  { float4 e2 = rsp[q][w];                                              \
    PRA = fmaf(pf##q.x, e2.x, PRA); PRA = fmaf(-pf##q.y, e2.y, PRA);    \
    PIA = fmaf(pf##q.x, e2.y, PIA); PIA = fmaf(pf##q.y, e2.x, PIA);     \
    PRA = fmaf(pf##q.z, e2.z, PRA); PRA = fmaf(-pf##q.w, e2.w, PRA);    \
    PIA = fmaf(pf##q.z, e2.w, PIA); PIA = fmaf(pf##q.w, e2.z, PIA);     \
    PRB = fmaf(pg##q.x, e2.x, PRB); PRB = fmaf(-pg##q.y, e2.y, PRB);    \
    PIB = fmaf(pg##q.x, e2.y, PIB); PIB = fmaf(pg##q.y, e2.x, PIB);     \
    PRB = fmaf(pg##q.z, e2.z, PRB); PRB = fmaf(-pg##q.w, e2.w, PRB);    \
    PIB = fmaf(pg##q.z, e2.w, PIB); PIB = fmaf(pg##q.w, e2.z, PIB); }

__global__ __launch_bounds__(TPB, 2) void qlayer_kernel(
    const float* __restrict__ x,      // [B,8]
    const float* __restrict__ th,     // [12]
    const float* __restrict__ W,      // [S_TOT,10]
    const float* __restrict__ bias,   // [10]
    float* __restrict__ out)          // [B,10]
{
  __shared__ float4 rsp[QG][MODES];       // packed Glynn row-sums, sign pre-folded
  __shared__ float4 ppt[QG][NPAIR];       // pair products rs_k[a]*rs_k[b]
  __shared__ float  prob_lds[S_TOT];      // boson-sampling distribution
  __shared__ float2 uc[MODES][NPH];       // Ucols
  __shared__ float  wred[NWAVE][NOUT];    // per-wave partials
  __shared__ unsigned       s_ea[NENT];   // staged schedule tables
  __shared__ unsigned       s_eb[NENT];
  __shared__ unsigned char  s_wr[NENT];
  __shared__ unsigned char  s_pairs[NPAIR];
  __shared__ float2         s_nl[7];

  const int b = blockIdx.x;
  const int t = threadIdx.x;

  // ---------- Phase A (wave 0: 60-lane column evolution) ∥ table staging ----------
  if (t < 64) {
    float sp_own = 0.f, cp_own = 0.f;
    if (t < 20) {
      float phi = (t < 12) ? th[t] : x[b * 8 + (t - 12)] * TWO_PI_F;
      sincosf(phi, &sp_own, &cp_own);
    }
    if (t < 60) {
      const int col = t / 12, m = t - col * 12;   // lane = col*12 + m
      float re = (m == col) ? 1.f : 0.f, im = 0.f;
      #pragma unroll
      for (int k = 0; k < 20; ++k) {
        const int mode = k % MODES;               // compile-time (k unrolled)
        float sp = __shfl(sp_own, k, 64);
        float cp = __shfl(cp_own, k, 64);
        float pre = re * cp - im * sp;            // phase rotation on `mode`
        float pim = re * sp + im * cp;
        re = (m == mode) ? pre : re;
        im = (m == mode) ? pim : im;
        int paired, pl;
        if ((k & 1) == 0) {                       // BS_EVEN: pairs (2j,2j+1)
          paired = 1; pl = t ^ 1;                 // col*12 even => lane^1 flips m^1
        } else {                                  // BS_ODD: pairs (1,2)..(9,10)
          paired = (m >= 1 && m <= 10);
          pl = paired ? (t - m + ((m & 1) ? m + 1 : m - 1)) : t;
        }
        float ore = __shfl(re, pl, 64);
        float oim = __shfl(im, pl, 64);
        if (paired) {                             // u_new = r*(u + i*u_partner)
          float nre = RS2 * (re - oim);
          float nim = RS2 * (im + ore);
          re = nre; im = nim;
        }
      }
      uc[m][col] = make_float2(re, im);
    }
  } else {
    // waves 1..7: stage schedule tables into LDS (overlaps Phase A)
    for (int i = t - 64; i < NENT; i += TPB - 64) {
      s_ea[i] = g_tab.ea[i];
      s_eb[i] = g_tab.eb[i];
      s_wr[i] = g_tab.wr[i];
    }
    if (t - 64 < NPAIR) s_pairs[t - 64] = g_tab.pairs[t - 64];
    if (t == 64) {
      #pragma unroll
      for (int i = 0; i < 7; ++i) s_nl[i] = g_normlut[i];
    }
  }
  __syncthreads();

  // ---------- Phase B+B2 merged (both read only uc) ----------
  if (t < QG * MODES) {   // rsp[q][m] for terms k0=2q, k1=2q+1
    const int q = t / MODES;
    const int m = t - q * MODES;
    const int k0 = 2 * q, k1 = k0 + 1;
    float r0 = uc[m][0].x, i0 = uc[m][0].y;   // delta_0 = +1
    float r1 = r0, i1 = i0;
    #pragma unroll
    for (int c = 1; c < NPH; ++c) {
      float ux = uc[m][c].x, uy = uc[m][c].y;
      float d0 = ((k0 >> (c - 1)) & 1) ? -1.f : 1.f;
      float d1 = ((k1 >> (c - 1)) & 1) ? -1.f : 1.f;
      r0 = fmaf(d0, ux, r0); i0 = fmaf(d0, uy, i0);
      r1 = fmaf(d1, ux, r1); i1 = fmaf(d1, uy, i1);
    }
    float sg0 = (__popc((unsigned)k0) & 1) ? -1.f : 1.f;
    float sg1 = (__popc((unsigned)k1) & 1) ? -1.f : 1.f;
    rsp[q][m] = make_float4(sg0 * r0, sg0 * i0, sg1 * r1, sg1 * i1);
  }
  auto do_ppt = [&](int i) {   // ppt[q][p]: recompute row-sums from uc (exact)
    const int q = i / NPAIR, p = i - q * NPAIR;
    const int ab = (int)s_pairs[p];
    const int a = ab >> 4, b2 = ab & 15;
    const int k0 = 2 * q, k1 = k0 + 1;
    float ar0 = uc[a][0].x,  ai0 = uc[a][0].y,  ar1 = ar0, ai1 = ai0;
    float br0 = uc[b2][0].x, bi0 = uc[b2][0].y, br1 = br0, bi1 = bi0;
    #pragma unroll
    for (int c = 1; c < NPH; ++c) {
      float d0 = ((k0 >> (c - 1)) & 1) ? -1.f : 1.f;
      float d1 = ((k1 >> (c - 1)) & 1) ? -1.f : 1.f;
      float ux = uc[a][c].x,  uy = uc[a][c].y;
      ar0 = fmaf(d0, ux, ar0); ai0 = fmaf(d0, uy, ai0);
      ar1 = fmaf(d1, ux, ar1); ai1 = fmaf(d1, uy, ai1);
      float vx = uc[b2][c].x, vy = uc[b2][c].y;
      br0 = fmaf(d0, vx, br0); bi0 = fmaf(d0, vy, bi0);
      br1 = fmaf(d1, vx, br1); bi1 = fmaf(d1, vy, bi1);
    }
    float sg0 = (__popc((unsigned)k0) & 1) ? -1.f : 1.f;
    float sg1 = (__popc((unsigned)k1) & 1) ? -1.f : 1.f;
    ar0 *= sg0; ai0 *= sg0; ar1 *= sg1; ai1 *= sg1;
    br0 *= sg0; bi0 *= sg0; br1 *= sg1; bi1 *= sg1;
    ppt[q][p] = make_float4(ar0 * br0 - ai0 * bi0, ar0 * bi0 + ai0 * br0,
                            ar1 * br1 - ai1 * bi1, ar1 * bi1 + ai1 * br1);
  };
  do_ppt(t);                     // items 0..511
  if (t >= 400) do_ppt(t + 112); // items 512..623
  __syncthreads();

  // ---------- Phase C: LPT-scheduled paired prefix permanents ----------
  auto do_entry = [&](int j) {
    const unsigned eA = s_ea[j];
    const unsigned eB = s_eb[j];
    const int wrj = (int)s_wr[j];
    const int w0 = wrj >> 4, w1 = wrj & 15;

    const int vA  = eA & 15;
    const int m2a = (eA >> 4) & 15, m1a = (eA >> 8) & 15, m0a = (eA >> 12) & 15;
    const int m2b = (eB >> 4) & 15, m1b = (eB >> 8) & 15, m0b = (eB >> 12) & 15;
    int siA = (int)((eA >> 16) & 0x1FFFu) + (w0 - vA);
    int siB = (int)((eB >> 16) & 0x1FFFu) + (w0 - vA);
    const float2 nlA = s_nl[eA >> 29];
    const float2 nlB = s_nl[eB >> 29];

    // unordered pair indices: off[a] = a*(25-a)/2
    const int p01a = (m0a * (25 - m0a)) / 2 + (m1a - m0a);
    const int p2va = (m2a * (25 - m2a)) / 2 + (vA  - m2a);
    const int p01b = (m0b * (25 - m0b)) / 2 + (m1b - m0b);
    const int p2vb = (m2b * (25 - m2b)) / 2 + (vA  - m2b);

    // 2x16 prefix Glynn products in 16 NAMED float4 regs
    float4 pf0, pf1, pf2, pf3, pf4, pf5, pf6, pf7;
    float4 pg0, pg1, pg2, pg3, pg4, pg5, pg6, pg7;
    PREFA(0) PREFA(1) PREFA(2) PREFA(3) PREFA(4) PREFA(5) PREFA(6) PREFA(7)
    PREFB(0) PREFB(1) PREFB(2) PREFB(3) PREFB(4) PREFB(5) PREFB(6) PREFB(7)

    float invnA = (w0 == vA) ? nlA.x : nlA.y;
    float invnB = (w0 == vA) ? nlB.x : nlB.y;
    for (int w = w0; w < w1; ++w, ++siA, ++siB) {
      float prA0 = 0.f, piA0 = 0.f, prA1 = 0.f, piA1 = 0.f;
      float prB0 = 0.f, piB0 = 0.f, prB1 = 0.f, piB1 = 0.f;
      WSTEP2(0, prA0, piA0, prB0, piB0) WSTEP2(1, prA0, piA0, prB0, piB0)
      WSTEP2(2, prA0, piA0, prB0, piB0) WSTEP2(3, prA0, piA0, prB0, piB0)
      WSTEP2(4, prA1, piA1, prB1, piB1) WSTEP2(5, prA1, piA1, prB1, piB1)
      WSTEP2(6, prA1, piA1, prB1, piB1) WSTEP2(7, prA1, piA1, prB1, piB1)
      float prA = prA0 + prA1, piA = piA0 + piA1;
      float prB = prB0 + prB1, piB = piB0 + piB1;
      prob_lds[siA] = (prA * prA + piA * piA) * invnA;
      prob_lds[siB] = (prB * prB + piB * piB) * invnB;
      invnA = nlA.y;
      invnB = nlB.y;
    }
  };
  // snake-LPT: slot t (desc-sorted), plus slot 1023-t for the 208 smallest
  do_entry(t);
  if (t >= 2 * TPB - NENT) do_entry(2 * TPB - 1 - t);   // t>=304 -> 512..719

  // prefetch Phase E round 0's W row before the barrier (addresses static)
  const float2* __restrict__ W2 = (const float2*)W;  // 40B rows, 8B-aligned
  const float2* wr0 = W2 + (size_t)t * 5;
  float2 a01 = wr0[0], a23 = wr0[1], a45 = wr0[2], a67 = wr0[3], a89 = wr0[4];
  __syncthreads();

  // ---------- Phase E: dense GEMV  out[b] = prob · W + bias ----------
  float po[NOUT];
  #pragma unroll
  for (int o = 0; o < NOUT; ++o) po[o] = 0.f;

  {                                    // round 0 (prefetched)
    const float p = prob_lds[t];
    po[0] = fmaf(p, a01.x, po[0]); po[1] = fmaf(p, a01.y, po[1]);
    po[2] = fmaf(p, a23.x, po[2]); po[3] = fmaf(p, a23.y, po[3]);
    po[4] = fmaf(p, a45.x, po[4]); po[5] = fmaf(p, a45.y, po[5]);
    po[6] = fmaf(p, a67.x, po[6]); po[7] = fmaf(p, a67.y, po[7]);
    po[8] = fmaf(p, a89.x, po[8]); po[9] = fmaf(p, a89.y, po[9]);
  }
  #pragma unroll 2
  for (int r = 1; r < 8; ++r) {        // rounds 1..7: s = r*512 + t
    const int s = r * TPB + t;
    const float p = prob_lds[s];
    const float2* wr2 = W2 + (size_t)s * 5;
    float2 w01 = wr2[0], w23 = wr2[1], w45 = wr2[2], w67 = wr2[3], w89 = wr2[4];
    po[0] = fmaf(p, w01.x, po[0]); po[1] = fmaf(p, w01.y, po[1]);
    po[2] = fmaf(p, w23.x, po[2]); po[3] = fmaf(p, w23.y, po[3]);
    po[4] = fmaf(p, w45.x, po[4]); po[5] = fmaf(p, w45.y, po[5]);
    po[6] = fmaf(p, w67.x, po[6]); po[7] = fmaf(p, w67.y, po[7]);
    po[8] = fmaf(p, w89.x, po[8]); po[9] = fmaf(p, w89.y, po[9]);
  }
  if (t < S_TOT - 8 * TPB) {           // tail: s = 4096 + t, 272 threads
    const int s = 8 * TPB + t;
    const float p = prob_lds[s];
    const float2* wr2 = W2 + (size_t)s * 5;
    float2 w01 = wr2[0], w23 = wr2[1], w45 = wr2[2], w67 = wr2[3], w89 = wr2[4];
    po[0] = fmaf(p, w01.x, po[0]); po[1] = fmaf(p, w01.y, po[1]);
    po[2] = fmaf(p, w23.x, po[2]); po[3] = fmaf(p, w23.y, po[3]);
    po[4] = fmaf(p, w45.x, po[4]); po[5] = fmaf(p, w45.y, po[5]);
    po[6] = fmaf(p, w67.x, po[6]); po[7] = fmaf(p, w67.y, po[7]);
    po[8] = fmaf(p, w89.x, po[8]); po[9] = fmaf(p, w89.y, po[9]);
  }

  // ---------- Phase D: block reduction ----------
  #pragma unroll
  for (int o = 0; o < NOUT; ++o) {
    float v = po[o];
    #pragma unroll
    for (int off = 32; off > 0; off >>= 1) v += __shfl_down(v, off, 64);
    po[o] = v;
  }
  const int lane = t & 63, wave = t >> 6;
  if (lane == 0) {
    #pragma unroll
    for (int o = 0; o < NOUT; ++o) wred[wave][o] = po[o];
  }
  __syncthreads();
  if (t < NOUT) {
    float acc = bias[t];
    #pragma unroll
    for (int w2 = 0; w2 < NWAVE; ++w2) acc += wred[w2][t];
    out[b * NOUT + t] = acc;
  }
}

extern "C" void kernel_launch(void* const* d_in, const int* in_sizes, int n_in,
                              void* d_out, int out_size, void* d_ws, size_t ws_size,
                              hipStream_t stream) {
  (void)n_in; (void)out_size; (void)d_ws; (void)ws_size;
  const float* x    = (const float*)d_in[0];
  const float* th   = (const float*)d_in[1];
  const float* W    = (const float*)d_in[2];
  const float* bias = (const float*)d_in[3];
  float* out        = (float*)d_out;
  const int B = in_sizes[0] / 8;   // 512
  qlayer_kernel<<<B, TPB, 0, stream>>>(x, th, W, bias, out);
}

// Round 12
// 21.117 us; speedup vs baseline: 1.1892x; 1.1892x over previous
//
#include <hip/hip_runtime.h>

// QuantumLayer: boson-sampling distribution + linear head.
//   x:[512,8] f32, thetas:[12] f32, W:[4368,10] f32, b:[10] f32 -> out:[512,10] f32
// Identities:
//   * Columns of U evolve independently under row-ops => evolve only cols 0..4.
//   * Glynn (16 terms, delta_0=+1); sign folded into rs; 2^-4 squared -> 1/256.
//   * Prefix factorization + same-v pairing: two prefixes share each rsp[q][w]
//     load burst; heavy pairs (v<=4) split; 16 named float4 regs (R2 lesson).
//   * R8: permanents -> prob_lds (no globals in hot loop), then dense GEMV.
//   * R10: 60-lane Phase A via __shfl; tables staged to LDS by waves 1-7
//     during Phase A; B+B2 merged; contiguous cstart schedule (R11's LPT
//     snake REGRESSED: 2x inlined hot body; reverted).
//   * R12: Phase E paired-row GEMV — rows (2s,2s+1) = five 16B-aligned
//     float4 loads (80B, 80s % 16 == 0), static unpack; 45 b64 -> ~22 b128
//     load instructions. Round-0 pair prefetched before the C->E barrier.
//   Falsified levers (R6/R7/R9/R11): more waves, more blocks, -28% LDS
//   traffic, LPT rebalance.

#define MODES 12
#define NPH   5
#define KG    16
#define QG    8         // KG/2 packed pairs
#define NPAIR 78        // unordered pairs a<=b
#define S_TOT 4368
#define TPB   512
#define NWAVE (TPB / 64)
#define NOUT  10
#define NENT  720       // 684 pairs + 36 splits (v<=4)

#define TWO_PI_F 6.28318530717958647692f
#define RS2      0.70710678118654752440f

// ---------------- compile-time schedule ----------------
constexpr int Cnk(int n, int r) {
  int p = 1;
  for (int i = 0; i < r; ++i) p = p * (n - i) / (i + 1);  // exact stepwise
  return p;
}

struct Tables {
  unsigned       ea[NENT];        // prefix A: code<<29 | sbase<<16 | m0<<12|m1<<8|m2<<4|v
  unsigned       eb[NENT];        // prefix B (== A for self-pairs)
  unsigned char  wr[NENT];        // w0<<4 | w1
  unsigned short cstart[TPB + 1];
  unsigned char  pairs[NPAIR];    // a<<4 | b
};

constexpr Tables make_tables() {
  Tables T{};
  int ne = 0;
  for (int v = 11; v >= 0; --v) {
    unsigned P[364] = {};
    int cnt = 0;
    for (int m0 = 0; m0 <= v; ++m0)
      for (int m1 = m0; m1 <= v; ++m1)
        for (int m2 = m1; m2 <= v; ++m2) {
          int sbase = 0;  // lex rank of (m0,m1,m2,v,v) in CWR(12,5)
          for (int q = 0;  q < m0; ++q) sbase += Cnk(15 - q, 4);
          for (int q = m0; q < m1; ++q) sbase += Cnk(14 - q, 3);
          for (int q = m1; q < m2; ++q) sbase += Cnk(13 - q, 2);
          for (int q = m2; q < v;  ++q) sbase += 12 - q;
          // norm code from (pm, run) of the 4-prefix (only 7 combos exist)
          int r1 = 1, pm = 1;
          r1 = (m1 == m0) ? r1 + 1 : 1; pm *= r1;
          r1 = (m2 == m1) ? r1 + 1 : 1; pm *= r1;
          r1 = (v  == m2) ? r1 + 1 : 1; pm *= r1;
          int code = 0;
          if (pm == 1)       code = 0;
          else if (pm == 2)  code = (r1 == 1) ? 1 : 2;
          else if (pm == 4)  code = 3;
          else if (pm == 6)  code = (r1 == 1) ? 4 : 5;
          else               code = 6;   // pm == 24
          P[cnt++] = ((unsigned)code << 29) | ((unsigned)sbase << 16) |
                     ((unsigned)m0 << 12) | ((unsigned)m1 << 8) |
                     ((unsigned)m2 << 4) | (unsigned)v;
        }
    const int np = (cnt + 1) / 2;
    for (int j = 0; j < np; ++j) {
      unsigned a = P[2 * j];
      unsigned b = (2 * j + 1 < cnt) ? P[2 * j + 1] : a;   // self-pair if odd
      if (v <= 4) {                       // split heavy pairs (tail fix)
        int mid = (v + 12) / 2;
        T.ea[ne] = a; T.eb[ne] = b; T.wr[ne] = (unsigned char)((v << 4) | mid);  ne++;
        T.ea[ne] = a; T.eb[ne] = b; T.wr[ne] = (unsigned char)((mid << 4) | 12); ne++;
      } else {
        T.ea[ne] = a; T.eb[ne] = b; T.wr[ne] = (unsigned char)((v << 4) | 12);   ne++;
      }
    }
  }
  // cost-balanced chunks; cost(entry) = 32 + 8*(w1-w0)
  long total = 0;
  for (int i = 0; i < NENT; ++i)
    total += 32 + 8 * ((T.wr[i] & 15) - (T.wr[i] >> 4));
  long cum = 0;
  int ci = 0;
  T.cstart[0] = 0;
  for (int i = 0; i < NENT; ++i) {
    cum += 32 + 8 * ((T.wr[i] & 15) - (T.wr[i] >> 4));
    while (ci < TPB - 1 && cum * TPB >= (long)(ci + 1) * total)
      T.cstart[++ci] = (unsigned short)(i + 1);
  }
  while (ci < TPB) T.cstart[++ci] = NENT;
  // unordered pair index table
  int pi = 0;
  for (int a = 0; a < MODES; ++a)
    for (int b = a; b < MODES; ++b)
      T.pairs[pi++] = (unsigned char)((a << 4) | b);
  return T;
}

__constant__ Tables g_tab = make_tables();

// (inv_first, inv_pm) per norm code: inv_pm = 1/(256*pm), inv_first = inv_pm/(run+1)
__constant__ float2 g_normlut[7] = {
  {1.f / 512.f,   1.f / 256.f},    // pm=1,  run=1
  {1.f / 1024.f,  1.f / 512.f},    // pm=2,  run=1
  {1.f / 1536.f,  1.f / 512.f},    // pm=2,  run=2
  {1.f / 3072.f,  1.f / 1024.f},   // pm=4,  run=2
  {1.f / 3072.f,  1.f / 1536.f},   // pm=6,  run=1
  {1.f / 6144.f,  1.f / 1536.f},   // pm=6,  run=3
  {1.f / 30720.f, 1.f / 6144.f},   // pm=24, run=4
};

// ---------------- device kernel ----------------
// prefix products from pair-product table (packed k0,k1)
#define PREFA(q)                                                    \
  { float4 A = ppt[q][p01a], B = ppt[q][p2va];                      \
    pf##q = make_float4(A.x*B.x - A.y*B.y, A.x*B.y + A.y*B.x,       \
                        A.z*B.z - A.w*B.w, A.z*B.w + A.w*B.z); }
#define PREFB(q)                                                    \
  { float4 A = ppt[q][p01b], B = ppt[q][p2vb];                      \
    pg##q = make_float4(A.x*B.x - A.y*B.y, A.x*B.y + A.y*B.x,       \
                        A.z*B.z - A.w*B.w, A.z*B.w + A.w*B.z); }

// one shared rsp load feeds both prefixes' FMAs
#define WSTEP2(q, PRA, PIA, PRB, PIB)                                   \
  { float4 e2 = rsp[q][w];                                              \
    PRA = fmaf(pf##q.x, e2.x, PRA); PRA = fmaf(-pf##q.y, e2.y, PRA);    \
    PIA = fmaf(pf##q.x, e2.y, PIA); PIA = fmaf(pf##q.y, e2.x, PIA);     \
    PRA = fmaf(pf##q.z, e2.z, PRA); PRA = fmaf(-pf##q.w, e2.w, PRA);    \
    PIA = fmaf(pf##q.z, e2.w, PIA); PIA = fmaf(pf##q.w, e2.z, PIA);     \
    PRB = fmaf(pg##q.x, e2.x, PRB); PRB = fmaf(-pg##q.y, e2.y, PRB);    \
    PIB = fmaf(pg##q.x, e2.y, PIB); PIB = fmaf(pg##q.y, e2.x, PIB);     \
    PRB = fmaf(pg##q.z, e2.z, PRB); PRB = fmaf(-pg##q.w, e2.w, PRB);    \
    PIB = fmaf(pg##q.z, e2.w, PIB); PIB = fmaf(pg##q.w, e2.z, PIB); }

// paired-row GEMV step: rows (2s,2s+1) from five float4s v0..v4
#define EPAIR(P0, P1, V0, V1, V2, V3, V4)                               \
  { po[0] = fmaf(P0, V0.x, po[0]); po[1] = fmaf(P0, V0.y, po[1]);       \
    po[2] = fmaf(P0, V0.z, po[2]); po[3] = fmaf(P0, V0.w, po[3]);       \
    po[4] = fmaf(P0, V1.x, po[4]); po[5] = fmaf(P0, V1.y, po[5]);       \
    po[6] = fmaf(P0, V1.z, po[6]); po[7] = fmaf(P0, V1.w, po[7]);       \
    po[8] = fmaf(P0, V2.x, po[8]); po[9] = fmaf(P0, V2.y, po[9]);       \
    po[0] = fmaf(P1, V2.z, po[0]); po[1] = fmaf(P1, V2.w, po[1]);       \
    po[2] = fmaf(P1, V3.x, po[2]); po[3] = fmaf(P1, V3.y, po[3]);       \
    po[4] = fmaf(P1, V3.z, po[4]); po[5] = fmaf(P1, V3.w, po[5]);       \
    po[6] = fmaf(P1, V4.x, po[6]); po[7] = fmaf(P1, V4.y, po[7]);       \
    po[8] = fmaf(P1, V4.z, po[8]); po[9] = fmaf(P1, V4.w, po[9]); }

__global__ __launch_bounds__(TPB, 2) void qlayer_kernel(
    const float* __restrict__ x,      // [B,8]
    const float* __restrict__ th,     // [12]
    const float* __restrict__ W,      // [S_TOT,10]
    const float* __restrict__ bias,   // [10]
    float* __restrict__ out)          // [B,10]
{
  __shared__ float4 rsp[QG][MODES];       // packed Glynn row-sums, sign pre-folded
  __shared__ float4 ppt[QG][NPAIR];       // pair products rs_k[a]*rs_k[b]
  __shared__ float  prob_lds[S_TOT];      // boson-sampling distribution
  __shared__ float2 uc[MODES][NPH];       // Ucols
  __shared__ float  wred[NWAVE][NOUT];    // per-wave partials
  __shared__ unsigned       s_ea[NENT];   // staged schedule tables
  __shared__ unsigned       s_eb[NENT];
  __shared__ unsigned char  s_wr[NENT];
  __shared__ unsigned short s_cs[TPB + 1];
  __shared__ unsigned char  s_pairs[NPAIR];
  __shared__ float2         s_nl[7];

  const int b = blockIdx.x;
  const int t = threadIdx.x;

  // ---------- Phase A (wave 0: 60-lane column evolution) ∥ table staging ----------
  if (t < 64) {
    float sp_own = 0.f, cp_own = 0.f;
    if (t < 20) {
      float phi = (t < 12) ? th[t] : x[b * 8 + (t - 12)] * TWO_PI_F;
      sincosf(phi, &sp_own, &cp_own);
    }
    if (t < 60) {
      const int col = t / 12, m = t - col * 12;   // lane = col*12 + m
      float re = (m == col) ? 1.f : 0.f, im = 0.f;
      #pragma unroll
      for (int k = 0; k < 20; ++k) {
        const int mode = k % MODES;               // compile-time (k unrolled)
        float sp = __shfl(sp_own, k, 64);
        float cp = __shfl(cp_own, k, 64);
        float pre = re * cp - im * sp;            // phase rotation on `mode`
        float pim = re * sp + im * cp;
        re = (m == mode) ? pre : re;
        im = (m == mode) ? pim : im;
        int paired, pl;
        if ((k & 1) == 0) {                       // BS_EVEN: pairs (2j,2j+1)
          paired = 1; pl = t ^ 1;                 // col*12 even => lane^1 flips m^1
        } else {                                  // BS_ODD: pairs (1,2)..(9,10)
          paired = (m >= 1 && m <= 10);
          pl = paired ? (t - m + ((m & 1) ? m + 1 : m - 1)) : t;
        }
        float ore = __shfl(re, pl, 64);
        float oim = __shfl(im, pl, 64);
        if (paired) {                             // u_new = r*(u + i*u_partner)
          float nre = RS2 * (re - oim);
          float nim = RS2 * (im + ore);
          re = nre; im = nim;
        }
      }
      uc[m][col] = make_float2(re, im);
    }
  } else {
    // waves 1..7: stage schedule tables into LDS (overlaps Phase A)
    for (int i = t - 64; i < NENT; i += TPB - 64) {
      s_ea[i] = g_tab.ea[i];
      s_eb[i] = g_tab.eb[i];
      s_wr[i] = g_tab.wr[i];
    }
    for (int i = t - 64; i < TPB + 1; i += TPB - 64) s_cs[i] = g_tab.cstart[i];
    if (t - 64 < NPAIR) s_pairs[t - 64] = g_tab.pairs[t - 64];
    if (t == 64) {
      #pragma unroll
      for (int i = 0; i < 7; ++i) s_nl[i] = g_normlut[i];
    }
  }
  __syncthreads();

  // ---------- Phase B+B2 merged (both read only uc) ----------
  if (t < QG * MODES) {   // rsp[q][m] for terms k0=2q, k1=2q+1
    const int q = t / MODES;
    const int m = t - q * MODES;
    const int k0 = 2 * q, k1 = k0 + 1;
    float r0 = uc[m][0].x, i0 = uc[m][0].y;   // delta_0 = +1
    float r1 = r0, i1 = i0;
    #pragma unroll
    for (int c = 1; c < NPH; ++c) {
      float ux = uc[m][c].x, uy = uc[m][c].y;
      float d0 = ((k0 >> (c - 1)) & 1) ? -1.f : 1.f;
      float d1 = ((k1 >> (c - 1)) & 1) ? -1.f : 1.f;
      r0 = fmaf(d0, ux, r0); i0 = fmaf(d0, uy, i0);
      r1 = fmaf(d1, ux, r1); i1 = fmaf(d1, uy, i1);
    }
    float sg0 = (__popc((unsigned)k0) & 1) ? -1.f : 1.f;
    float sg1 = (__popc((unsigned)k1) & 1) ? -1.f : 1.f;
    rsp[q][m] = make_float4(sg0 * r0, sg0 * i0, sg1 * r1, sg1 * i1);
  }
  auto do_ppt = [&](int i) {   // ppt[q][p]: recompute row-sums from uc (exact)
    const int q = i / NPAIR, p = i - q * NPAIR;
    const int ab = (int)s_pairs[p];
    const int a = ab >> 4, b2 = ab & 15;
    const int k0 = 2 * q, k1 = k0 + 1;
    float ar0 = uc[a][0].x,  ai0 = uc[a][0].y,  ar1 = ar0, ai1 = ai0;
    float br0 = uc[b2][0].x, bi0 = uc[b2][0].y, br1 = br0, bi1 = bi0;
    #pragma unroll
    for (int c = 1; c < NPH; ++c) {
      float d0 = ((k0 >> (c - 1)) & 1) ? -1.f : 1.f;
      float d1 = ((k1 >> (c - 1)) & 1) ? -1.f : 1.f;
      float ux = uc[a][c].x,  uy = uc[a][c].y;
      ar0 = fmaf(d0, ux, ar0); ai0 = fmaf(d0, uy, ai0);
      ar1 = fmaf(d1, ux, ar1); ai1 = fmaf(d1, uy, ai1);
      float vx = uc[b2][c].x, vy = uc[b2][c].y;
      br0 = fmaf(d0, vx, br0); bi0 = fmaf(d0, vy, bi0);
      br1 = fmaf(d1, vx, br1); bi1 = fmaf(d1, vy, bi1);
    }
    float sg0 = (__popc((unsigned)k0) & 1) ? -1.f : 1.f;
    float sg1 = (__popc((unsigned)k1) & 1) ? -1.f : 1.f;
    ar0 *= sg0; ai0 *= sg0; ar1 *= sg1; ai1 *= sg1;
    br0 *= sg0; bi0 *= sg0; br1 *= sg1; bi1 *= sg1;
    ppt[q][p] = make_float4(ar0 * br0 - ai0 * bi0, ar0 * bi0 + ai0 * br0,
                            ar1 * br1 - ai1 * bi1, ar1 * bi1 + ai1 * br1);
  };
  do_ppt(t);                     // items 0..511
  if (t >= 400) do_ppt(t + 112); // items 512..623
  __syncthreads();

  // ---------- Phase C: paired prefix permanents -> prob_lds ----------
  {
    const int beg = s_cs[t];
    const int end = s_cs[t + 1];
    for (int j = beg; j < end; ++j) {
      const unsigned eA = s_ea[j];
      const unsigned eB = s_eb[j];
      const int wrj = (int)s_wr[j];
      const int w0 = wrj >> 4, w1 = wrj & 15;

      const int vA  = eA & 15;
      const int m2a = (eA >> 4) & 15, m1a = (eA >> 8) & 15, m0a = (eA >> 12) & 15;
      const int m2b = (eB >> 4) & 15, m1b = (eB >> 8) & 15, m0b = (eB >> 12) & 15;
      int siA = (int)((eA >> 16) & 0x1FFFu) + (w0 - vA);
      int siB = (int)((eB >> 16) & 0x1FFFu) + (w0 - vA);
      const float2 nlA = s_nl[eA >> 29];
      const float2 nlB = s_nl[eB >> 29];

      // unordered pair indices: off[a] = a*(25-a)/2
      const int p01a = (m0a * (25 - m0a)) / 2 + (m1a - m0a);
      const int p2va = (m2a * (25 - m2a)) / 2 + (vA  - m2a);
      const int p01b = (m0b * (25 - m0b)) / 2 + (m1b - m0b);
      const int p2vb = (m2b * (25 - m2b)) / 2 + (vA  - m2b);

      // 2x16 prefix Glynn products in 16 NAMED float4 regs
      float4 pf0, pf1, pf2, pf3, pf4, pf5, pf6, pf7;
      float4 pg0, pg1, pg2, pg3, pg4, pg5, pg6, pg7;
      PREFA(0) PREFA(1) PREFA(2) PREFA(3) PREFA(4) PREFA(5) PREFA(6) PREFA(7)
      PREFB(0) PREFB(1) PREFB(2) PREFB(3) PREFB(4) PREFB(5) PREFB(6) PREFB(7)

      float invnA = (w0 == vA) ? nlA.x : nlA.y;
      float invnB = (w0 == vA) ? nlB.x : nlB.y;
      for (int w = w0; w < w1; ++w, ++siA, ++siB) {
        float prA0 = 0.f, piA0 = 0.f, prA1 = 0.f, piA1 = 0.f;
        float prB0 = 0.f, piB0 = 0.f, prB1 = 0.f, piB1 = 0.f;
        WSTEP2(0, prA0, piA0, prB0, piB0) WSTEP2(1, prA0, piA0, prB0, piB0)
        WSTEP2(2, prA0, piA0, prB0, piB0) WSTEP2(3, prA0, piA0, prB0, piB0)
        WSTEP2(4, prA1, piA1, prB1, piB1) WSTEP2(5, prA1, piA1, prB1, piB1)
        WSTEP2(6, prA1, piA1, prB1, piB1) WSTEP2(7, prA1, piA1, prB1, piB1)
        float prA = prA0 + prA1, piA = piA0 + piA1;
        float prB = prB0 + prB1, piB = piB0 + piB1;
        prob_lds[siA] = (prA * prA + piA * piA) * invnA;
        prob_lds[siB] = (prB * prB + piB * piB) * invnB;
        invnA = nlA.y;
        invnB = nlB.y;
      }
    }
  }

  // prefetch Phase E round 0's W pair (rows 2t, 2t+1) before the barrier
  const float4* __restrict__ W4 = (const float4*)W;   // pairs are 16B-aligned
  const float4* wp0 = W4 + (size_t)t * 5;             // = W + 2t*10 floats
  float4 b0 = wp0[0], b1 = wp0[1], b2v = wp0[2], b3 = wp0[3], b4 = wp0[4];
  __syncthreads();

  // ---------- Phase E: paired-row dense GEMV  out[b] = prob · W + bias ----------
  float po[NOUT];
  #pragma unroll
  for (int o = 0; o < NOUT; ++o) po[o] = 0.f;

  {                                    // pair round 0 (prefetched): s = 2t, 2t+1
    const float p0 = prob_lds[2 * t], p1 = prob_lds[2 * t + 1];
    EPAIR(p0, p1, b0, b1, b2v, b3, b4)
  }
  #pragma unroll 2
  for (int r = 1; r < 4; ++r) {        // pair rounds 1..3: sp = r*512 + t
    const int sp = r * TPB + t;        // covers s = 2sp, 2sp+1  (< 4096)
    const float p0 = prob_lds[2 * sp], p1 = prob_lds[2 * sp + 1];
    const float4* wp = W4 + (size_t)sp * 5;
    float4 v0 = wp[0], v1 = wp[1], v2 = wp[2], v3 = wp[3], v4 = wp[4];
    EPAIR(p0, p1, v0, v1, v2, v3, v4)
  }
  if (t < S_TOT / 2 - 4 * TPB) {       // tail pairs: sp = 2048 + t, 136 threads
    const int sp = 4 * TPB + t;
    const float p0 = prob_lds[2 * sp], p1 = prob_lds[2 * sp + 1];
    const float4* wp = W4 + (size_t)sp * 5;
    float4 v0 = wp[0], v1 = wp[1], v2 = wp[2], v3 = wp[3], v4 = wp[4];
    EPAIR(p0, p1, v0, v1, v2, v3, v4)
  }

  // ---------- Phase D: block reduction ----------
  #pragma unroll
  for (int o = 0; o < NOUT; ++o) {
    float v = po[o];
    #pragma unroll
    for (int off = 32; off > 0; off >>= 1) v += __shfl_down(v, off, 64);
    po[o] = v;
  }
  const int lane = t & 63, wave = t >> 6;
  if (lane == 0) {
    #pragma unroll
    for (int o = 0; o < NOUT; ++o) wred[wave][o] = po[o];
  }
  __syncthreads();
  if (t < NOUT) {
    float acc = bias[t];
    #pragma unroll
    for (int w2 = 0; w2 < NWAVE; ++w2) acc += wred[w2][t];
    out[b * NOUT + t] = acc;
  }
}

extern "C" void kernel_launch(void* const* d_in, const int* in_sizes, int n_in,
                              void* d_out, int out_size, void* d_ws, size_t ws_size,
                              hipStream_t stream) {
  (void)n_in; (void)out_size; (void)d_ws; (void)ws_size;
  const float* x    = (const float*)d_in[0];
  const float* th   = (const float*)d_in[1];
  const float* W    = (const float*)d_in[2];
  const float* bias = (const float*)d_in[3];
  float* out        = (float*)d_out;
  const int B = in_sizes[0] / 8;   // 512
  qlayer_kernel<<<B, TPB, 0, stream>>>(x, th, W, bias, out);
}